// Round 8
// baseline (201.047 us; speedup 1.0000x reference)
//
#include <hip/hip_runtime.h>
#include <cstdint>
#include <climits>

static constexpr int    NC    = 2000000;   // clause id range (fixed by reference)
static constexpr int    NXCD  = 8;
static constexpr size_t NCPAD = 2000000;   // replica stride (64-aligned: 2e6 % 64 == 0)
static_assert(NC % 16 == 0, "check_k vector path needs NC % 16 == 0");

typedef int   int4v   __attribute__((ext_vector_type(4)));
typedef float float4v __attribute__((ext_vector_type(4)));

// ws layout (bytes)
static constexpr size_t OFF_FLAGS = 0;                          // u8 flags[NXCD][NCPAD]
static constexpr size_t FLAGS_BY  = (size_t)NXCD * NCPAD;       // 16,000,000
static constexpr size_t OFF_CNT   = OFF_FLAGS + FLAGS_BY;       // u32 counts[NC] (fallback)
static constexpr size_t CNT_BY    = (size_t)NC * 4;             //  8,000,000
static constexpr size_t OFF_XBB   = OFF_CNT + CNT_BY;           // bit-packed xb

__device__ __forceinline__ int xcc_id() {
    int x;
    asm volatile("s_getreg_b32 %0, hwreg(HW_REG_XCC_ID)" : "=s"(x));
    return x & (NXCD - 1);
}

// Zero flag replicas, bit-pack xb (xb = floor(xv/0.50001f), true f32 divide to
// match the reference), init ctrl. counts[] cleared only on the (gated) exact path.
__global__ __launch_bounds__(256) void init_k(const float* __restrict__ xv, int nv,
                                              uint8_t* __restrict__ xbb,
                                              int4v* __restrict__ flags16,
                                              int* __restrict__ ctrl) {
    int stride = gridDim.x * blockDim.x;
    int i0 = blockIdx.x * blockDim.x + threadIdx.x;
    int nf16 = (int)(FLAGS_BY / 16);
    int4v z = {0, 0, 0, 0};
    for (int i = i0; i < nf16; i += stride) flags16[i] = z;
    int nbytes = nv >> 3;
    const float4v* p4 = (const float4v*)xv;
    for (int i = i0; i < nbytes; i += stride) {
        float4v a = p4[2 * i], b = p4[2 * i + 1];
        uint32_t m = 0;
        #pragma unroll
        for (int j = 0; j < 4; ++j)
            m |= ((uint32_t)(int)floorf(a[j] / 0.50001f)) << j;
        #pragma unroll
        for (int j = 0; j < 4; ++j)
            m |= ((uint32_t)(int)floorf(b[j] / 0.50001f)) << (4 + j);
        xbb[i] = (uint8_t)m;
    }
    if (i0 == 0) {
        if (nv & 7) {
            uint32_t m = 0;
            for (int j = 0; j < (nv & 7); ++j)
                m |= ((uint32_t)(int)floorf(xv[(nbytes << 3) + j] / 0.50001f)) << j;
            xbb[nbytes] = (uint8_t)m;
        }
        ctrl[0] = 0;        // zero_found
        ctrl[1] = INT_MAX;  // minslot (exact path)
    }
}

// Flag pass: per satisfied edge, ONE plain byte store into this XCD's private
// replica. No atomics, no LDS, no return values — fire-and-forget.
__global__ __launch_bounds__(256) void flag_k(const int* __restrict__ adj_pos,
                                              const int* __restrict__ adj_neg,
                                              const uint32_t* __restrict__ xbw,
                                              uint8_t* __restrict__ flags,
                                              int ne_p, int ne_n) {
    uint8_t* __restrict__ my = flags + (size_t)xcc_id() * NCPAD;
    int gid = blockIdx.x * 256 + threadIdx.x;
    int gstride = gridDim.x * 256;

    const int* adjs[2] = {adj_pos, adj_neg};
    int nes[2] = {ne_p, ne_n};
    for (int pol = 0; pol < 2; ++pol) {
        const int* adj = adjs[pol];
        int ne = nes[pol];
        int neg = pol;
        int n4 = ((ne & 3) == 0) ? (ne >> 2) : 0;   // vector path needs aligned rows
        const int4v* c4 = (const int4v*)adj;
        const int4v* v4 = (const int4v*)(adj + ne);
        for (int i = gid; i < n4; i += gstride) {
            int4v c = __builtin_nontemporal_load(c4 + i);
            int4v v = __builtin_nontemporal_load(v4 + i);
            #pragma unroll
            for (int j = 0; j < 4; ++j) {
                int cc = c[j], vv = v[j];
                int bit = (int)((xbw[vv >> 5] >> (vv & 31)) & 1u);
                if (bit != neg) my[cc] = (uint8_t)1;
            }
        }
        for (int e = (n4 << 2) + gid; e < ne; e += gstride) {   // scalar tail
            int cc = adj[e], vv = adj[ne + e];
            int bit = (int)((xbw[vv >> 5] >> (vv & 31)) & 1u);
            if (bit != neg) my[cc] = (uint8_t)1;
        }
    }
}

// Check pass: OR the 8 replicas; any zero byte in [0, NC) => some clause has
// zero satisfied literals => min == 0.
__global__ __launch_bounds__(256) void check_k(const uint8_t* __restrict__ flags,
                                               int* __restrict__ zero_found) {
    int i = blockIdx.x * blockDim.x + threadIdx.x;
    int n16 = NC / 16;
    uint32_t z = 0;
    if (i < n16) {
        int4v w = {0, 0, 0, 0};
        #pragma unroll
        for (int x = 0; x < NXCD; ++x) {
            const int4v* f = (const int4v*)(flags + (size_t)x * NCPAD);
            w |= f[i];
        }
        #pragma unroll
        for (int j = 0; j < 4; ++j) {
            uint32_t u = (uint32_t)w[j];
            z |= (u - 0x01010101u) & ~u & 0x80808080u;   // any-zero-byte test
        }
    }
    if (__any(z != 0) && (threadIdx.x & 63) == 0) atomicOr(zero_found, 1);
}

// ---- exact-count path (launched every call; early-exits when zero_found) ----
__global__ __launch_bounds__(256) void fbz_k(uint32_t* __restrict__ counts,
                                             const int* __restrict__ zf) {
    if (*zf) return;
    int stride = gridDim.x * blockDim.x;
    for (int i = blockIdx.x * blockDim.x + threadIdx.x; i < NC; i += stride)
        counts[i] = 0u;
}

template<int NEG>
__global__ __launch_bounds__(256) void fb_edge_k(const int* __restrict__ adj,
                                                 const uint32_t* __restrict__ xbw,
                                                 uint32_t* __restrict__ counts,
                                                 int ne, const int* __restrict__ zf) {
    if (*zf) return;
    int stride = gridDim.x * blockDim.x;
    int i0 = blockIdx.x * blockDim.x + threadIdx.x;
    for (int e = i0; e < ne; e += stride) {
        int c = adj[e];
        int v = adj[ne + e];
        int bit = (int)((xbw[v >> 5] >> (v & 31)) & 1u);
        if (bit != NEG) atomicAdd(&counts[c], 1u);
    }
}

__global__ __launch_bounds__(256) void fb_min_k(const uint32_t* __restrict__ counts,
                                                int* __restrict__ minslot,
                                                const int* __restrict__ zf) {
    if (*zf) return;
    int stride = gridDim.x * blockDim.x;
    int i0 = blockIdx.x * blockDim.x + threadIdx.x;
    int lo = INT_MAX;
    for (int i = i0; i < NC; i += stride) lo = min(lo, (int)counts[i]);
    for (int off = 32; off > 0; off >>= 1) lo = min(lo, __shfl_down(lo, off));
    if ((threadIdx.x & 63) == 0) atomicMin(minslot, lo);
}

__global__ void fin_k(const int* __restrict__ ctrl, float* __restrict__ out) {
    out[0] = ctrl[0] ? 0.0f : (float)ctrl[1];
}

extern "C" void kernel_launch(void* const* d_in, const int* in_sizes, int n_in,
                              void* d_out, int out_size, void* d_ws, size_t ws_size,
                              hipStream_t stream) {
    const float* xv    = (const float*)d_in[0];
    const int* adj_pos = (const int*)d_in[1];   // int32 per harness contract
    const int* adj_neg = (const int*)d_in[2];
    float* out = (float*)d_out;

    const int nv   = in_sizes[0];
    const int ne_p = in_sizes[1] / 2;   // rows: [clause, var]
    const int ne_n = in_sizes[2] / 2;

    char* ws = (char*)d_ws;
    dim3 blk(256);

    const size_t xbb_by  = (((size_t)nv + 7) / 8 + 64) & ~63ull;
    const size_t off_ctl = OFF_XBB + xbb_by;
    const size_t need    = off_ctl + 64;

    if (ws_size >= need) {
        uint8_t*  flags = (uint8_t*) (ws + OFF_FLAGS);
        uint32_t* cnts  = (uint32_t*)(ws + OFF_CNT);
        uint8_t*  xbb   = (uint8_t*) (ws + OFF_XBB);
        int*      ctrl  = (int*)     (ws + off_ctl);   // [0]=zero_found [1]=minslot
        const uint32_t* xbw = (const uint32_t*)xbb;

        init_k<<<2048, blk, 0, stream>>>(xv, nv, xbb, (int4v*)flags, ctrl);
        flag_k<<<2048, blk, 0, stream>>>(adj_pos, adj_neg, xbw, flags, ne_p, ne_n);
        check_k<<<(NC / 16 + 255) / 256, blk, 0, stream>>>(flags, ctrl);
        // Exact path: launched every call, early-exits when a zero clause exists.
        fbz_k<<<2048, blk, 0, stream>>>(cnts, ctrl);
        fb_edge_k<0><<<2048, blk, 0, stream>>>(adj_pos, xbw, cnts, ne_p, ctrl);
        fb_edge_k<1><<<2048, blk, 0, stream>>>(adj_neg, xbw, cnts, ne_n, ctrl);
        fb_min_k<<<2048, blk, 0, stream>>>(cnts, ctrl + 1, ctrl);
        fin_k<<<1, 1, 0, stream>>>(ctrl, out);
    } else {
        // Minimal-ws fallback: exact path only (ungated).
        uint32_t* cnts = (uint32_t*)ws;
        uint8_t*  xbb  = (uint8_t*) (ws + CNT_BY);
        int*      ctrl = (int*)     (ws + CNT_BY + xbb_by);
        const uint32_t* xbw = (const uint32_t*)xbb;
        init_k<<<2048, blk, 0, stream>>>(xv, nv, xbb, (int4v*)cnts /*scratch*/, ctrl);
        fbz_k<<<2048, blk, 0, stream>>>(cnts, ctrl);            // ctrl[0]==0 -> runs
        fb_edge_k<0><<<2048, blk, 0, stream>>>(adj_pos, xbw, cnts, ne_p, ctrl);
        fb_edge_k<1><<<2048, blk, 0, stream>>>(adj_neg, xbw, cnts, ne_n, ctrl);
        fb_min_k<<<2048, blk, 0, stream>>>(cnts, ctrl + 1, ctrl);
        fin_k<<<1, 1, 0, stream>>>(ctrl, out);
    }
}